// Round 1
// baseline (9810.399 us; speedup 1.0000x reference)
//
#include <hip/hip_runtime.h>
#include <cstdint>
#include <cstddef>

// Problem dims (fixed)
#define B_   256
#define T_   512
#define F_   128
#define CU_  512
#define DU_  512
#define NG   2048   // 4*DU
#define KX   640    // F+CU

using short8 = __attribute__((ext_vector_type(8))) short;
using f32x4  = __attribute__((ext_vector_type(4))) float;

__device__ unsigned g_bar[128];   // 8 chains, 64B-padded (index mg*16)

__device__ __forceinline__ unsigned short f2bf(float x) {
    union { float f; unsigned u; } v; v.f = x;
    unsigned r = v.u + 0x7fffu + ((v.u >> 16) & 1u);   // RNE
    return (unsigned short)(r >> 16);
}
__device__ __forceinline__ float bf2f(unsigned short s) {
    union { unsigned u; float f; } v; v.u = ((unsigned)s) << 16;
    return v.f;
}
__device__ __forceinline__ float sigf(float x) {
    return 1.0f / (1.0f + exp2f(-1.44269504f * x));
}
__device__ __forceinline__ float tanh_fast(float x) {
    return 1.0f - 2.0f / (1.0f + exp2f(2.88539008f * x));
}

// ---------------------------------------------------------------------------
// Prep: fp32 [K][N] -> bf16 [N][K] transposed cast (K-contiguous for B-frags)
__global__ __launch_bounds__(256) void k_transpose(const float* __restrict__ src,
                                                   unsigned short* __restrict__ dst,
                                                   int K, int N) {
    __shared__ float tile[32][33];
    int x = threadIdx.x & 31, y = threadIdx.x >> 5;
    int n0 = blockIdx.x * 32, k0 = blockIdx.y * 32;
    #pragma unroll
    for (int i = 0; i < 4; ++i)
        tile[y + i * 8][x] = src[(size_t)(k0 + y + i * 8) * N + n0 + x];
    __syncthreads();
    #pragma unroll
    for (int i = 0; i < 4; ++i)
        dst[(size_t)(n0 + y + i * 8) * K + k0 + x] = f2bf(tile[x][y + i * 8]);
}

// hs[0] = bf16(h0); zero chain barriers
__global__ __launch_bounds__(256) void k_init(const float* __restrict__ h0,
                                              unsigned short* __restrict__ hs0) {
    int i = blockIdx.x * 256 + threadIdx.x;   // 512 blocks * 256 = 131072
    hs0[i] = f2bf(h0[i]);
    if (i < 128) g_bar[i] = 0;
}

// ---------------------------------------------------------------------------
// K1: Zx[m][n] = X[m][:] @ W[:, n] + b[n]  (unchanged, proven)
__global__ __launch_bounds__(256) void k_zx(const float* __restrict__ teacher,
                                            const float* __restrict__ conductor,
                                            const float* __restrict__ bias,
                                            const unsigned short* __restrict__ Wt,
                                            unsigned short* __restrict__ Zx) {
    __shared__ unsigned short a_lds[128][40];
    __shared__ unsigned short b_lds[128][40];
    const int tid = threadIdx.x;
    const int lane = tid & 63, w = tid >> 6;
    const int l15 = lane & 15, q = lane >> 4;
    const int n0 = blockIdx.x * 128;
    const int m0 = blockIdx.y * 128;
    const int t  = m0 >> 8;
    const int bb = m0 & 255;
    const int r  = tid >> 1;
    const int ch = (tid & 1) * 16;

    const int mw = (w >> 1) * 64, nw = (w & 1) * 64;

    f32x4 acc[4][4];
    #pragma unroll
    for (int i = 0; i < 4; ++i)
        #pragma unroll
        for (int j = 0; j < 4; ++j) acc[i][j] = (f32x4){0.f, 0.f, 0.f, 0.f};

    for (int kb = 0; kb < 20; ++kb) {
        int k0 = kb * 32 + ch;
        float av[16];
        if (k0 < F_) {
            if (t == 0) {
                #pragma unroll
                for (int j = 0; j < 16; ++j) av[j] = 0.f;
            } else {
                const float* s = teacher + ((size_t)(bb + r) * T_ + (t - 1)) * F_ + k0;
                #pragma unroll
                for (int j = 0; j < 16; ++j) av[j] = s[j];
            }
        } else {
            const float* s = conductor + ((size_t)(bb + r) * T_ + t) * CU_ + (k0 - F_);
            #pragma unroll
            for (int j = 0; j < 16; ++j) av[j] = s[j];
        }
        short8 s0, s1;
        #pragma unroll
        for (int j = 0; j < 8; ++j) { s0[j] = (short)f2bf(av[j]); s1[j] = (short)f2bf(av[j + 8]); }
        *(short8*)&a_lds[r][ch]     = s0;
        *(short8*)&a_lds[r][ch + 8] = s1;
        const unsigned short* bs = Wt + (size_t)(n0 + r) * KX + kb * 32 + ch;
        *(short8*)&b_lds[r][ch]     = *(const short8*)bs;
        *(short8*)&b_lds[r][ch + 8] = *(const short8*)(bs + 8);
        __syncthreads();
        short8 af[4], bfr[4];
        #pragma unroll
        for (int mt = 0; mt < 4; ++mt)
            af[mt] = *(const short8*)&a_lds[mw + mt * 16 + l15][q * 8];
        #pragma unroll
        for (int nt = 0; nt < 4; ++nt)
            bfr[nt] = *(const short8*)&b_lds[nw + nt * 16 + l15][q * 8];
        #pragma unroll
        for (int mt = 0; mt < 4; ++mt)
            #pragma unroll
            for (int nt = 0; nt < 4; ++nt)
                acc[mt][nt] = __builtin_amdgcn_mfma_f32_16x16x32_bf16(af[mt], bfr[nt], acc[mt][nt], 0, 0, 0);
        __syncthreads();
    }
    #pragma unroll
    for (int nt = 0; nt < 4; ++nt) {
        int col = n0 + nw + nt * 16 + l15;
        float bv = bias[col];
        #pragma unroll
        for (int mt = 0; mt < 4; ++mt) {
            int row = m0 + mw + mt * 16 + q * 4;
            #pragma unroll
            for (int rr = 0; rr < 4; ++rr)
                Zx[(size_t)(row + rr) * NG + col] = f2bf(acc[mt][nt][rr] + bv);
        }
    }
}

// ---------------------------------------------------------------------------
// K2: PERSISTENT recurrence. 256 blocks = 8 m-chains (32 rows) x 32 d-groups
// (16 cols). Wave w = gate w; its U slice (16 cols x K=512) lives in 64 VGPRs
// for all 512 steps. c lives in 2 regs/thread. Chain-local 32-block barrier
// per step (monotonic counter, agent scope). Zx for step t+1 prefetched into
// regs before the spin-wait.
__global__ __launch_bounds__(256) void k_rec(const unsigned short* __restrict__ Zx,
                                             unsigned short* __restrict__ hs,
                                             const unsigned short* __restrict__ Ut,
                                             const float* __restrict__ c0,
                                             float* __restrict__ hT,
                                             float* __restrict__ cT) {
    __shared__ float zbuf[4][32][18];   // [gate][m][d], pad 18: 2-way max (free)
    const int tid  = threadIdx.x;
    const int lane = tid & 63, gate = tid >> 6;
    const int l15  = lane & 15, q = lane >> 4;
    const int mg   = blockIdx.x & 7;        // chain id (XCD-local under %8 map)
    const int dg   = blockIdx.x >> 3;       // 0..31
    const int m0   = mg * 32;
    const int dsub = dg * 16;

    // ---- U fragments: register-resident for the whole sequence ----
    short8 bU[16];
    {
        const unsigned short* ub = Ut + (size_t)(gate * DU_ + dsub + l15) * DU_ + q * 8;
        #pragma unroll
        for (int ki = 0; ki < 16; ++ki)
            bU[ki] = *(const short8*)(ub + ki * 32);
    }

    // ---- cell state: 2 cells/thread, register-resident ----
    const int em = tid >> 3;            // local m 0..31
    const int ed = (tid & 7) * 2;       // local d 0,2,..,14
    float cr0 = c0[(size_t)(m0 + em) * DU_ + dsub + ed];
    float cr1 = c0[(size_t)(m0 + em) * DU_ + dsub + ed + 1];

    // ---- Zx prefetch (acc-init values; depends only on t) ----
    const unsigned short* zxb = Zx + (size_t)(m0 + q * 4) * NG + gate * DU_ + dsub + l15;
    unsigned short zp0[4], zp1[4];
    #pragma unroll
    for (int rr = 0; rr < 4; ++rr) {
        zp0[rr] = zxb[(size_t)rr * NG];
        zp1[rr] = zxb[(size_t)(16 + rr) * NG];
    }

    for (int t = 0; t < T_; ++t) {
        // acc init = Zx (x@W + b), then accumulate h@U on top
        f32x4 acc0, acc1;
        #pragma unroll
        for (int rr = 0; rr < 4; ++rr) { acc0[rr] = bf2f(zp0[rr]); acc1[rr] = bf2f(zp1[rr]); }

        const unsigned short* hrow = hs + (size_t)t * (B_ * DU_)
                                        + (size_t)(m0 + l15) * DU_ + q * 8;
        #pragma unroll
        for (int ki = 0; ki < 16; ++ki) {
            short8 a0 = *(const short8*)(hrow + ki * 32);
            short8 a1 = *(const short8*)(hrow + 16 * DU_ + ki * 32);
            acc0 = __builtin_amdgcn_mfma_f32_16x16x32_bf16(a0, bU[ki], acc0, 0, 0, 0);
            acc1 = __builtin_amdgcn_mfma_f32_16x16x32_bf16(a1, bU[ki], acc1, 0, 0, 0);
        }

        // prefetch Zx for t+1 (hidden under LDS exchange + barrier)
        if (t + 1 < T_) {
            const unsigned short* zn = zxb + (size_t)(t + 1) * ((size_t)B_ * NG);
            #pragma unroll
            for (int rr = 0; rr < 4; ++rr) {
                zp0[rr] = zn[(size_t)rr * NG];
                zp1[rr] = zn[(size_t)(16 + rr) * NG];
            }
        }

        // gate exchange via LDS
        #pragma unroll
        for (int rr = 0; rr < 4; ++rr) {
            zbuf[gate][q * 4 + rr][l15]      = acc0[rr];
            zbuf[gate][16 + q * 4 + rr][l15] = acc1[rr];
        }
        __syncthreads();

        // epilogue: this thread's 2 (m,d) cells
        float zi0 = zbuf[0][em][ed], zi1 = zbuf[0][em][ed + 1];
        float zf0 = zbuf[1][em][ed], zf1 = zbuf[1][em][ed + 1];
        float zg0 = zbuf[2][em][ed], zg1 = zbuf[2][em][ed + 1];
        float zo0 = zbuf[3][em][ed], zo1 = zbuf[3][em][ed + 1];
        float cn0 = sigf(zf0) * cr0 + sigf(zi0) * tanh_fast(zg0);
        float cn1 = sigf(zf1) * cr1 + sigf(zi1) * tanh_fast(zg1);
        cr0 = cn0; cr1 = cn1;
        float h0v = sigf(zo0) * tanh_fast(cn0);
        float h1v = sigf(zo1) * tanh_fast(cn1);
        unsigned pack = (unsigned)f2bf(h0v) | ((unsigned)f2bf(h1v) << 16);
        size_t hidx = (size_t)(t + 1) * (B_ * DU_) + (size_t)(m0 + em) * DU_ + dsub + ed;
        *(unsigned*)&hs[hidx] = pack;

        if (t == T_ - 1) {
            size_t ci = (size_t)(m0 + em) * DU_ + dsub + ed;
            hT[ci] = h0v; hT[ci + 1] = h1v;
            cT[ci] = cn0; cT[ci + 1] = cn1;
        } else {
            __syncthreads();   // all waves' h stores drained (vmcnt0 before barrier)
            if (tid == 0) {
                __threadfence();   // release: push h past this XCD's L2
                __hip_atomic_fetch_add(&g_bar[mg * 16], 1u, __ATOMIC_RELAXED,
                                       __HIP_MEMORY_SCOPE_AGENT);
                unsigned tgt = 32u * (unsigned)(t + 1);
                while (__hip_atomic_load(&g_bar[mg * 16], __ATOMIC_RELAXED,
                                         __HIP_MEMORY_SCOPE_AGENT) < tgt) {
                    __builtin_amdgcn_s_sleep(1);
                }
                __threadfence();   // acquire: invalidate stale L1/L2 lines
            }
            __syncthreads();       // releases block; also fences zbuf reuse
        }
    }
}

// ---------------------------------------------------------------------------
// K3: out[b][t][f] = sigmoid(hs[t+1][b][:] @ Wo[:, f] + bo[f])  (unchanged)
__global__ __launch_bounds__(256) void k_out(const unsigned short* __restrict__ hs,
                                             const unsigned short* __restrict__ Wot,
                                             const float* __restrict__ bo,
                                             float* __restrict__ out) {
    const int tid = threadIdx.x;
    const int lane = tid & 63, w = tid >> 6;
    const int l15 = lane & 15, q = lane >> 4;
    const int m0 = blockIdx.x * 64 + w * 16;
    const unsigned short* hbase = hs + (size_t)(B_ * DU_);

    f32x4 acc[8];
    #pragma unroll
    for (int nt = 0; nt < 8; ++nt) acc[nt] = (f32x4){0.f, 0.f, 0.f, 0.f};

    for (int ki = 0; ki < 16; ++ki) {
        int k = ki * 32 + q * 8;
        short8 a = *(const short8*)&hbase[(size_t)(m0 + l15) * DU_ + k];
        #pragma unroll
        for (int nt = 0; nt < 8; ++nt) {
            short8 b = *(const short8*)&Wot[(size_t)(nt * 16 + l15) * DU_ + k];
            acc[nt] = __builtin_amdgcn_mfma_f32_16x16x32_bf16(a, b, acc[nt], 0, 0, 0);
        }
    }
    #pragma unroll
    for (int nt = 0; nt < 8; ++nt) {
        int f = nt * 16 + l15;
        float bv = bo[f];
        #pragma unroll
        for (int rr = 0; rr < 4; ++rr) {
            int m = m0 + q * 4 + rr;
            int b = m & 255, t = m >> 8;
            out[(size_t)b * (T_ * F_) + (size_t)t * F_ + f] = sigf(acc[nt][rr] + bv);
        }
    }
}

// ---------------------------------------------------------------------------
extern "C" void kernel_launch(void* const* d_in, const int* in_sizes, int n_in,
                              void* d_out, int out_size, void* d_ws, size_t ws_size,
                              hipStream_t stream) {
    const float* conductor = (const float*)d_in[0];
    const float* teacher   = (const float*)d_in[1];
    const float* h0        = (const float*)d_in[2];
    const float* c0        = (const float*)d_in[3];
    const float* W         = (const float*)d_in[4];
    const float* U         = (const float*)d_in[5];
    const float* b         = (const float*)d_in[6];
    const float* Wo        = (const float*)d_in[7];
    const float* bo        = (const float*)d_in[8];

    float* out = (float*)d_out;
    float* hT  = out + (size_t)B_ * T_ * F_;
    float* cT  = hT + B_ * DU_;

    char* ws = (char*)d_ws;
    unsigned short* Zx  = (unsigned short*)ws;                                   // 512 MB
    unsigned short* hs  = (unsigned short*)(ws + (size_t)536870912);             // 128.25 MB
    unsigned short* Wt  = (unsigned short*)(ws + 536870912 + (size_t)134479872); // [2048][640]
    unsigned short* Ut  = Wt + (size_t)NG * KX;                                  // [2048][512]
    unsigned short* Wot = Ut + (size_t)NG * DU_;                                 // [128][512]

    k_transpose<<<dim3(64, 20), 256, 0, stream>>>(W,  Wt,  KX,  NG);
    k_transpose<<<dim3(64, 16), 256, 0, stream>>>(U,  Ut,  DU_, NG);
    k_transpose<<<dim3(4, 16),  256, 0, stream>>>(Wo, Wot, DU_, F_);
    k_init<<<512, 256, 0, stream>>>(h0, hs);

    k_zx<<<dim3(16, 1024), 256, 0, stream>>>(teacher, conductor, b, Wt, Zx);

    // persistent recurrence: one cooperative launch replaces 512 k_step launches
    {
        const unsigned short* ZxA = Zx;
        unsigned short*       hsA = hs;
        const unsigned short* UtA = Ut;
        const float*          c0A = c0;
        float*                hTA = hT;
        float*                cTA = cT;
        void* kargs[] = { &ZxA, &hsA, &UtA, &c0A, &hTA, &cTA };
        hipLaunchCooperativeKernel((const void*)k_rec, dim3(256), dim3(256),
                                   kargs, 0, stream);
    }

    k_out<<<2048, 256, 0, stream>>>(hs, Wot, bo, out);
}

// Round 2
// 4274.107 us; speedup vs baseline: 2.2953x; 2.2953x over previous
//
#include <hip/hip_runtime.h>
#include <cstdint>
#include <cstddef>

// Problem dims (fixed)
#define B_   256
#define T_   512
#define F_   128
#define CU_  512
#define DU_  512
#define NG   2048   // 4*DU
#define KX   640    // F+CU

using short8 = __attribute__((ext_vector_type(8))) short;
using f32x4  = __attribute__((ext_vector_type(4))) float;

__device__ unsigned g_bar[128];   // 8 chains, 64B-padded (index mg*16)

__device__ __forceinline__ unsigned short f2bf(float x) {
    union { float f; unsigned u; } v; v.f = x;
    unsigned r = v.u + 0x7fffu + ((v.u >> 16) & 1u);   // RNE
    return (unsigned short)(r >> 16);
}
__device__ __forceinline__ float bf2f(unsigned short s) {
    union { unsigned u; float f; } v; v.u = ((unsigned)s) << 16;
    return v.f;
}
__device__ __forceinline__ float sigf(float x) {
    return 1.0f / (1.0f + exp2f(-1.44269504f * x));
}
__device__ __forceinline__ float tanh_fast(float x) {
    return 1.0f - 2.0f / (1.0f + exp2f(2.88539008f * x));
}

// Coherent (LLC-level) 16B load: bypass L1+L2. Data NOT ready until an
// explicit s_waitcnt; every use is guarded by waitcnt + sched_barrier (rule 18).
__device__ __forceinline__ void gload_b128_sc(short8* d, const unsigned short* p) {
    asm volatile("global_load_dwordx4 %0, %1, off sc0 sc1" : "=v"(*d) : "v"(p));
}
// Plain (cached) 2B load, issue-order controlled via asm volatile.
__device__ __forceinline__ void gload_u16(unsigned* d, const unsigned short* p) {
    asm volatile("global_load_ushort %0, %1, off" : "=v"(*d) : "v"(p));
}

// ---------------------------------------------------------------------------
// Prep: fp32 [K][N] -> bf16 [N][K] transposed cast (K-contiguous for B-frags)
__global__ __launch_bounds__(256) void k_transpose(const float* __restrict__ src,
                                                   unsigned short* __restrict__ dst,
                                                   int K, int N) {
    __shared__ float tile[32][33];
    int x = threadIdx.x & 31, y = threadIdx.x >> 5;
    int n0 = blockIdx.x * 32, k0 = blockIdx.y * 32;
    #pragma unroll
    for (int i = 0; i < 4; ++i)
        tile[y + i * 8][x] = src[(size_t)(k0 + y + i * 8) * N + n0 + x];
    __syncthreads();
    #pragma unroll
    for (int i = 0; i < 4; ++i)
        dst[(size_t)(n0 + y + i * 8) * K + k0 + x] = f2bf(tile[x][y + i * 8]);
}

// hs[0] = bf16(h0); zero chain barriers
__global__ __launch_bounds__(256) void k_init(const float* __restrict__ h0,
                                              unsigned short* __restrict__ hs0) {
    int i = blockIdx.x * 256 + threadIdx.x;   // 512 blocks * 256 = 131072
    hs0[i] = f2bf(h0[i]);
    if (i < 128) g_bar[i] = 0;
}

// ---------------------------------------------------------------------------
// K1: Zx[m][n] = X[m][:] @ W[:, n] + b[n]  (unchanged, proven)
__global__ __launch_bounds__(256) void k_zx(const float* __restrict__ teacher,
                                            const float* __restrict__ conductor,
                                            const float* __restrict__ bias,
                                            const unsigned short* __restrict__ Wt,
                                            unsigned short* __restrict__ Zx) {
    __shared__ unsigned short a_lds[128][40];
    __shared__ unsigned short b_lds[128][40];
    const int tid = threadIdx.x;
    const int lane = tid & 63, w = tid >> 6;
    const int l15 = lane & 15, q = lane >> 4;
    const int n0 = blockIdx.x * 128;
    const int m0 = blockIdx.y * 128;
    const int t  = m0 >> 8;
    const int bb = m0 & 255;
    const int r  = tid >> 1;
    const int ch = (tid & 1) * 16;

    const int mw = (w >> 1) * 64, nw = (w & 1) * 64;

    f32x4 acc[4][4];
    #pragma unroll
    for (int i = 0; i < 4; ++i)
        #pragma unroll
        for (int j = 0; j < 4; ++j) acc[i][j] = (f32x4){0.f, 0.f, 0.f, 0.f};

    for (int kb = 0; kb < 20; ++kb) {
        int k0 = kb * 32 + ch;
        float av[16];
        if (k0 < F_) {
            if (t == 0) {
                #pragma unroll
                for (int j = 0; j < 16; ++j) av[j] = 0.f;
            } else {
                const float* s = teacher + ((size_t)(bb + r) * T_ + (t - 1)) * F_ + k0;
                #pragma unroll
                for (int j = 0; j < 16; ++j) av[j] = s[j];
            }
        } else {
            const float* s = conductor + ((size_t)(bb + r) * T_ + t) * CU_ + (k0 - F_);
            #pragma unroll
            for (int j = 0; j < 16; ++j) av[j] = s[j];
        }
        short8 s0, s1;
        #pragma unroll
        for (int j = 0; j < 8; ++j) { s0[j] = (short)f2bf(av[j]); s1[j] = (short)f2bf(av[j + 8]); }
        *(short8*)&a_lds[r][ch]     = s0;
        *(short8*)&a_lds[r][ch + 8] = s1;
        const unsigned short* bs = Wt + (size_t)(n0 + r) * KX + kb * 32 + ch;
        *(short8*)&b_lds[r][ch]     = *(const short8*)bs;
        *(short8*)&b_lds[r][ch + 8] = *(const short8*)(bs + 8);
        __syncthreads();
        short8 af[4], bfr[4];
        #pragma unroll
        for (int mt = 0; mt < 4; ++mt)
            af[mt] = *(const short8*)&a_lds[mw + mt * 16 + l15][q * 8];
        #pragma unroll
        for (int nt = 0; nt < 4; ++nt)
            bfr[nt] = *(const short8*)&b_lds[nw + nt * 16 + l15][q * 8];
        #pragma unroll
        for (int mt = 0; mt < 4; ++mt)
            #pragma unroll
            for (int nt = 0; nt < 4; ++nt)
                acc[mt][nt] = __builtin_amdgcn_mfma_f32_16x16x32_bf16(af[mt], bfr[nt], acc[mt][nt], 0, 0, 0);
        __syncthreads();
    }
    #pragma unroll
    for (int nt = 0; nt < 4; ++nt) {
        int col = n0 + nw + nt * 16 + l15;
        float bv = bias[col];
        #pragma unroll
        for (int mt = 0; mt < 4; ++mt) {
            int row = m0 + mw + mt * 16 + q * 4;
            #pragma unroll
            for (int rr = 0; rr < 4; ++rr)
                Zx[(size_t)(row + rr) * NG + col] = f2bf(acc[mt][nt][rr] + bv);
        }
    }
}

// ---------------------------------------------------------------------------
// K2: PERSISTENT recurrence. 256 blocks = 8 m-chains (32 rows) x 32 d-groups.
// NO cache-wide fences: h communicated via write-through (sc0 sc1) stores +
// L2-bypass (sc0 sc1) loads; chain barrier = relaxed agent atomic counter.
__global__ __launch_bounds__(256, 1) void k_rec(const unsigned short* __restrict__ Zx,
                                                unsigned short* __restrict__ hs,
                                                const unsigned short* __restrict__ Ut,
                                                const float* __restrict__ c0,
                                                float* __restrict__ hT,
                                                float* __restrict__ cT) {
    __shared__ float zbuf[4][32][18];   // [gate][m][d], pad 18
    const int tid  = threadIdx.x;
    const int lane = tid & 63, gate = tid >> 6;
    const int l15  = lane & 15, q = lane >> 4;
    const int mg   = blockIdx.x & 7;        // chain id (XCD-local under %8 map)
    const int dg   = blockIdx.x >> 3;       // 0..31
    const int m0   = mg * 32;
    const int dsub = dg * 16;

    // ---- U fragments: register-resident for the whole sequence ----
    short8 bU[16];
    {
        const unsigned short* ub = Ut + (size_t)(gate * DU_ + dsub + l15) * DU_ + q * 8;
        #pragma unroll
        for (int ki = 0; ki < 16; ++ki)
            bU[ki] = *(const short8*)(ub + ki * 32);
    }

    // ---- cell state: 2 cells/thread, register-resident fp32 ----
    const int em = tid >> 3;            // local m 0..31
    const int ed = (tid & 7) * 2;       // local d 0,2,..,14
    float cr0 = c0[(size_t)(m0 + em) * DU_ + dsub + ed];
    float cr1 = c0[(size_t)(m0 + em) * DU_ + dsub + ed + 1];

    // ---- Zx double-buffered prefetch regs ----
    const unsigned short* zxb = Zx + (size_t)(m0 + q * 4) * NG + gate * DU_ + dsub + l15;
    unsigned zc0[4], zc1[4], zn0[4], zn1[4];
    #pragma unroll
    for (int rr = 0; rr < 4; ++rr) {
        zc0[rr] = zxb[(size_t)rr * NG];
        zc1[rr] = zxb[(size_t)(16 + rr) * NG];
        zn0[rr] = 0; zn1[rr] = 0;
    }

    unsigned* bar = &g_bar[mg * 16];

    for (int t = 0; t < T_; ++t) {
        // ---- issue 32 coherent h loads (LLC), then 8 plain Zx(t+1) loads ----
        const unsigned short* hrow = hs + (size_t)t * (B_ * DU_)
                                        + (size_t)(m0 + l15) * DU_ + q * 8;
        short8 a0[16], a1[16];
        #pragma unroll
        for (int ki = 0; ki < 16; ++ki) gload_b128_sc(&a0[ki], hrow + ki * 32);
        #pragma unroll
        for (int ki = 0; ki < 16; ++ki) gload_b128_sc(&a1[ki], hrow + 16 * DU_ + ki * 32);

        // acc init from current Zx (overlaps load latency)
        f32x4 acc0, acc1;
        #pragma unroll
        for (int rr = 0; rr < 4; ++rr) {
            acc0[rr] = bf2f((unsigned short)zc0[rr]);
            acc1[rr] = bf2f((unsigned short)zc1[rr]);
        }

        if (t + 1 < T_) {
            const unsigned short* zn = zxb + (size_t)(t + 1) * ((size_t)B_ * NG);
            #pragma unroll
            for (int rr = 0; rr < 4; ++rr) {
                gload_u16(&zn0[rr], zn + (size_t)rr * NG);
                gload_u16(&zn1[rr], zn + (size_t)(16 + rr) * NG);
            }
            // h loads (first 32 issued) retired; zn (last 8) may stay in flight
            asm volatile("s_waitcnt vmcnt(8)" ::: "memory");
        } else {
            asm volatile("s_waitcnt vmcnt(0)" ::: "memory");
        }
        __builtin_amdgcn_sched_barrier(0);   // rule 18: keep MFMA below the wait

        #pragma unroll
        for (int ki = 0; ki < 16; ++ki) {
            acc0 = __builtin_amdgcn_mfma_f32_16x16x32_bf16(a0[ki], bU[ki], acc0, 0, 0, 0);
            acc1 = __builtin_amdgcn_mfma_f32_16x16x32_bf16(a1[ki], bU[ki], acc1, 0, 0, 0);
        }

        // ---- gate exchange via LDS ----
        #pragma unroll
        for (int rr = 0; rr < 4; ++rr) {
            zbuf[gate][q * 4 + rr][l15]      = acc0[rr];
            zbuf[gate][16 + q * 4 + rr][l15] = acc1[rr];
        }
        __syncthreads();                     // also drains zn loads (vmcnt 0)
        __builtin_amdgcn_sched_barrier(0);   // zn regs valid only after the drain
        #pragma unroll
        for (int rr = 0; rr < 4; ++rr) { zc0[rr] = zn0[rr]; zc1[rr] = zn1[rr]; }

        // ---- epilogue: this thread's 2 (m,d) cells ----
        float zi0 = zbuf[0][em][ed], zi1 = zbuf[0][em][ed + 1];
        float zf0 = zbuf[1][em][ed], zf1 = zbuf[1][em][ed + 1];
        float zg0 = zbuf[2][em][ed], zg1 = zbuf[2][em][ed + 1];
        float zo0 = zbuf[3][em][ed], zo1 = zbuf[3][em][ed + 1];
        float cn0 = sigf(zf0) * cr0 + sigf(zi0) * tanh_fast(zg0);
        float cn1 = sigf(zf1) * cr1 + sigf(zi1) * tanh_fast(zg1);
        cr0 = cn0; cr1 = cn1;
        float h0v = sigf(zo0) * tanh_fast(cn0);
        float h1v = sigf(zo1) * tanh_fast(cn1);
        unsigned pack = (unsigned)f2bf(h0v) | ((unsigned)f2bf(h1v) << 16);
        size_t hidx = (size_t)(t + 1) * (B_ * DU_) + (size_t)(m0 + em) * DU_ + dsub + ed;
        // write-through to LLC (agent-coherent), no cache maintenance
        __hip_atomic_store((unsigned*)&hs[hidx], pack, __ATOMIC_RELAXED,
                           __HIP_MEMORY_SCOPE_AGENT);

        if (t == T_ - 1) {
            size_t ci = (size_t)(m0 + em) * DU_ + dsub + ed;
            hT[ci] = h0v; hT[ci + 1] = h1v;
            cT[ci] = cn0; cT[ci + 1] = cn1;
        } else {
            __syncthreads();   // vmcnt(0): all h stores ack'd at coherent point
            if (tid == 0) {
                __hip_atomic_fetch_add(bar, 1u, __ATOMIC_RELAXED,
                                       __HIP_MEMORY_SCOPE_AGENT);
                unsigned tgt = 32u * (unsigned)(t + 1);
                while (__hip_atomic_load(bar, __ATOMIC_RELAXED,
                                         __HIP_MEMORY_SCOPE_AGENT) < tgt) {
                    __builtin_amdgcn_s_sleep(1);
                }
            }
            __syncthreads();   // releases block; also WAR-guards zbuf reuse
        }
    }
}

// ---------------------------------------------------------------------------
// K3: out[b][t][f] = sigmoid(hs[t+1][b][:] @ Wo[:, f] + bo[f])  (unchanged)
__global__ __launch_bounds__(256) void k_out(const unsigned short* __restrict__ hs,
                                             const unsigned short* __restrict__ Wot,
                                             const float* __restrict__ bo,
                                             float* __restrict__ out) {
    const int tid = threadIdx.x;
    const int lane = tid & 63, w = tid >> 6;
    const int l15 = lane & 15, q = lane >> 4;
    const int m0 = blockIdx.x * 64 + w * 16;
    const unsigned short* hbase = hs + (size_t)(B_ * DU_);

    f32x4 acc[8];
    #pragma unroll
    for (int nt = 0; nt < 8; ++nt) acc[nt] = (f32x4){0.f, 0.f, 0.f, 0.f};

    for (int ki = 0; ki < 16; ++ki) {
        int k = ki * 32 + q * 8;
        short8 a = *(const short8*)&hbase[(size_t)(m0 + l15) * DU_ + k];
        #pragma unroll
        for (int nt = 0; nt < 8; ++nt) {
            short8 b = *(const short8*)&Wot[(size_t)(nt * 16 + l15) * DU_ + k];
            acc[nt] = __builtin_amdgcn_mfma_f32_16x16x32_bf16(a, b, acc[nt], 0, 0, 0);
        }
    }
    #pragma unroll
    for (int nt = 0; nt < 8; ++nt) {
        int f = nt * 16 + l15;
        float bv = bo[f];
        #pragma unroll
        for (int rr = 0; rr < 4; ++rr) {
            int m = m0 + q * 4 + rr;
            int b = m & 255, t = m >> 8;
            out[(size_t)b * (T_ * F_) + (size_t)t * F_ + f] = sigf(acc[nt][rr] + bv);
        }
    }
}

// ---------------------------------------------------------------------------
extern "C" void kernel_launch(void* const* d_in, const int* in_sizes, int n_in,
                              void* d_out, int out_size, void* d_ws, size_t ws_size,
                              hipStream_t stream) {
    const float* conductor = (const float*)d_in[0];
    const float* teacher   = (const float*)d_in[1];
    const float* h0        = (const float*)d_in[2];
    const float* c0        = (const float*)d_in[3];
    const float* W         = (const float*)d_in[4];
    const float* U         = (const float*)d_in[5];
    const float* b         = (const float*)d_in[6];
    const float* Wo        = (const float*)d_in[7];
    const float* bo        = (const float*)d_in[8];

    float* out = (float*)d_out;
    float* hT  = out + (size_t)B_ * T_ * F_;
    float* cT  = hT + B_ * DU_;

    char* ws = (char*)d_ws;
    unsigned short* Zx  = (unsigned short*)ws;                                   // 512 MB
    unsigned short* hs  = (unsigned short*)(ws + (size_t)536870912);             // 128.25 MB
    unsigned short* Wt  = (unsigned short*)(ws + 536870912 + (size_t)134479872); // [2048][640]
    unsigned short* Ut  = Wt + (size_t)NG * KX;                                  // [2048][512]
    unsigned short* Wot = Ut + (size_t)NG * DU_;                                 // [128][512]

    k_transpose<<<dim3(64, 20), 256, 0, stream>>>(W,  Wt,  KX,  NG);
    k_transpose<<<dim3(64, 16), 256, 0, stream>>>(U,  Ut,  DU_, NG);
    k_transpose<<<dim3(4, 16),  256, 0, stream>>>(Wo, Wot, DU_, F_);
    k_init<<<512, 256, 0, stream>>>(h0, hs);

    k_zx<<<dim3(16, 1024), 256, 0, stream>>>(teacher, conductor, b, Wt, Zx);

    // persistent recurrence: one cooperative launch replaces 512 step launches
    {
        const unsigned short* ZxA = Zx;
        unsigned short*       hsA = hs;
        const unsigned short* UtA = Ut;
        const float*          c0A = c0;
        float*                hTA = hT;
        float*                cTA = cT;
        void* kargs[] = { &ZxA, &hsA, &UtA, &c0A, &hTA, &cTA };
        hipLaunchCooperativeKernel((const void*)k_rec, dim3(256), dim3(256),
                                   kargs, 0, stream);
    }

    k_out<<<2048, 256, 0, stream>>>(hs, Wot, bo, out);
}